// Round 6
// baseline (126.747 us; speedup 1.0000x reference)
//
#include <hip/hip_runtime.h>
#include <stdint.h>

// B=256, T=512, f32. v11 = v10 with the per-tile vmcnt fixed: v10's vmcnt(7)
// forced all 24 scattered stores of the previous tile to drain before each
// tile's compute (stores sit ahead of the prefetched y in the vmcnt FIFO),
// serializing the pipeline. v11 waits vmcnt(28)/(20): y_t is complete iff
// outstanding <= 24 stores + 7 next-y = 31 (24 at the tail), so 28/20 leaves
// stores + next-y in flight across tiles. Also: A-frag bf16 packing via u32
// lane writes (Frag union) instead of short inserts. Everything else = v10:
// 4 tiles/wave, 512 blocks, weights staged once/block, y double-buffered,
// H reuses y-buffer head, scattered stores, 2 blocks/CU.
#define NTOK (256 * 512)
#define TPB 256

typedef short bf16x8 __attribute__((ext_vector_type(8)));
typedef float f32x4 __attribute__((ext_vector_type(4)));
typedef unsigned int u32x4 __attribute__((ext_vector_type(4)));
typedef unsigned short u16;
typedef unsigned int u32;

union Frag { bf16x8 h; u32x4 w; };

#define B1_U16 10752   // 28 chunks * 48 cols * 8 u16
#define B2_U16 6144    // 8 chunks * 96 cols * 8 u16
#define W_U16 (B1_U16 + B2_U16)               // 16896 u16 = 33792 B, 2112 chunks
#define YB_U16 2816                           // 5632 B y tile buffer

__device__ __forceinline__ u16 f2bf(float f) {
    u32 u = __float_as_uint(f);
    return (u16)((u + 0x7fffu + ((u >> 16) & 1u)) >> 16);  // rne
}
__device__ __forceinline__ u32 cvtpk(float lo, float hi) {
    u32 r;
    asm("v_cvt_pk_bf16_f32 %0, %1, %2" : "=v"(r) : "v"(lo), "v"(hi));
    return r;
}
__device__ __forceinline__ void gll16(const void* g, void* l) {
    __builtin_amdgcn_global_load_lds(
        (const __attribute__((address_space(1))) void*)g,
        (__attribute__((address_space(3))) void*)l, 16, 0, 0);
}
__device__ __forceinline__ void gll4(const void* g, void* l) {
    __builtin_amdgcn_global_load_lds(
        (const __attribute__((address_space(1))) void*)g,
        (__attribute__((address_space(3))) void*)l, 4, 0, 0);
}

// stage one 16-token y tile (contiguous 5632 B) into LDS: exactly 7 VMEM ops
__device__ __forceinline__ void stage_y(const float* ysrc, u16* dst_u16, int lane) {
    const char* yt = (const char*)ysrc;
    char* dst = (char*)dst_u16;
    #pragma unroll
    for (int j = 0; j < 5; j++)
        gll16(yt + j * 1024 + lane * 16, dst + j * 1024);
    #pragma unroll
    for (int k = 0; k < 2; k++)
        gll4(yt + 5120 + k * 256 + lane * 4, dst + 5120 + k * 256);
}

// ---------------- prep: build fragment-ordered bf16 weight image ----------------
__global__ __launch_bounds__(256, 1)
void prep_weights(const float* __restrict__ Wxh, const float* __restrict__ bxh,
                  const float* __restrict__ Wwh, const float* __restrict__ bwh,
                  const float* __restrict__ Wyh, const float* __restrict__ byh,
                  const float* __restrict__ Whl, const float* __restrict__ bhl,
                  u16* __restrict__ ws)
{
    int e = blockIdx.x * 256 + threadIdx.x;
    if (e < B1_U16) {
        int j = e & 7, n = (e >> 3) % 48, kc = e / 384;
        int k = kc * 8 + j;                  // k = 2*d + ch for k<176
        float v;
        if (k < 176)       v = Wyh[n * 176 + (k & 1) * 88 + (k >> 1)];
        else if (k < 192)  v = Wxh[n * 16 + (k - 176)];   // x-onehot rows
        else if (k < 208)  v = Wwh[n * 16 + (k - 192)];   // w-onehot rows
        else if (k == 208) v = bxh[n] + bwh[n] + byh[n];  // bias row
        else               v = 0.0f;
        ws[e] = f2bf(v);
    } else if (e < B1_U16 + B2_U16) {
        int e2 = e - B1_U16;
        int j = e2 & 7, dd = (e2 >> 3) % 96, kc = e2 / 768;
        int k = kc * 8 + j;
        float v = 0.0f;
        if (dd < 88) {
            if (k < 48)       v = Whl[dd * 48 + k];
            else if (k == 48) v = bhl[dd];
        }
        ws[e] = f2bf(v);
    }
}

// ---------------- per-tile compute (inlined 4x) ----------------
__device__ __forceinline__ void compute_tile(
    const u16* __restrict__ ldsw,   // weight image base in LDS
    u16* __restrict__ sb,           // this tile's y buffer; head reused for H
    float wc00, float wc01, float wc02, float wc10, float wc11, float wc12,
    float bc0, float bc1, int xv, int wv, int q, int c, int tb,
    float* __restrict__ out)
{
    const float* yr = (const float*)sb + c * 88;          // lane's token row
    const u16* f1 = ldsw + (q * 48 + c) * 8;
    const u16* f2 = ldsw + B1_U16 + (q * 96 + c) * 8;

    f32x4 h0 = {0, 0, 0, 0}, h1 = {0, 0, 0, 0}, h2 = {0, 0, 0, 0};
    #pragma unroll
    for (int ks = 0; ks < 7; ks++) {
        Frag af;
        if (ks < 5) {
            const int d0 = 16 * ks + 4 * q;
            float p0 = (d0 == 0) ? 0.0f : yr[d0 - 1];
            f32x4 v4 = *(const f32x4*)(yr + d0);
            float p5 = yr[d0 + 4];                        // d0+4 <= 80 < 88
            float p[6] = {p0, v4[0], v4[1], v4[2], v4[3], p5};
            #pragma unroll
            for (int i = 0; i < 4; i++) {
                float c0 = fmaf(wc00, p[i], fmaf(wc01, p[i + 1], fmaf(wc02, p[i + 2], bc0)));
                float c1 = fmaf(wc10, p[i], fmaf(wc11, p[i + 1], fmaf(wc12, p[i + 2], bc1)));
                af.w[i] = cvtpk(fmaxf(c0, 0.0f), fmaxf(c1, 0.0f));
            }
        } else if (ks == 5) {
            if (q < 2) {
                const int d0 = 80 + 4 * q;
                float p0 = yr[d0 - 1];
                f32x4 v4 = *(const f32x4*)(yr + d0);
                float p5 = (q == 0) ? yr[84] : 0.0f;      // right edge pad at d=87
                float p[6] = {p0, v4[0], v4[1], v4[2], v4[3], p5};
                #pragma unroll
                for (int i = 0; i < 4; i++) {
                    float c0 = fmaf(wc00, p[i], fmaf(wc01, p[i + 1], fmaf(wc02, p[i + 2], bc0)));
                    float c1 = fmaf(wc10, p[i], fmaf(wc11, p[i + 1], fmaf(wc12, p[i + 2], bc1)));
                    af.w[i] = cvtpk(fmaxf(c0, 0.0f), fmaxf(c1, 0.0f));
                }
            } else {
                const int base = (q - 2) * 8;
                #pragma unroll
                for (int i = 0; i < 4; i++) {
                    u32 lo = (base + 2 * i     == xv) ? 0x3F80u : 0u;
                    u32 hi = (base + 2 * i + 1 == xv) ? 0x3F800000u : 0u;
                    af.w[i] = lo | hi;
                }
            }
        } else {
            if (q < 2) {
                const int base = q * 8;
                #pragma unroll
                for (int i = 0; i < 4; i++) {
                    u32 lo = (base + 2 * i     == wv) ? 0x3F80u : 0u;
                    u32 hi = (base + 2 * i + 1 == wv) ? 0x3F800000u : 0u;
                    af.w[i] = lo | hi;
                }
            } else {
                af.w = (u32x4){(q == 2) ? 0x3F80u : 0u, 0u, 0u, 0u};
            }
        }
        bf16x8 b0 = *(const bf16x8*)(f1 + (ks * 192 +  0) * 8);
        bf16x8 b1 = *(const bf16x8*)(f1 + (ks * 192 + 16) * 8);
        bf16x8 b2 = *(const bf16x8*)(f1 + (ks * 192 + 32) * 8);
        h0 = __builtin_amdgcn_mfma_f32_16x16x32_bf16(af.h, b0, h0, 0, 0, 0);
        h1 = __builtin_amdgcn_mfma_f32_16x16x32_bf16(af.h, b1, h1, 0, 0, 0);
        h2 = __builtin_amdgcn_mfma_f32_16x16x32_bf16(af.h, b2, h2, 0, 0, 0);
    }

    // H in A-frag layout, reusing buffer head (this wave's y rows fully read
    // above; same-wave LDS ops execute in program order, so this is safe)
    u16* sW = sb;
    if (q < 2) {   // chunk 6: bias-one at k2=48 (j==0); chunk 7: zeros
        uint4 hz = make_uint4((q == 0) ? 0x3F80u : 0u, 0, 0, 0);
        *(uint4*)(sW + ((6 + q) * 16 + c) * 8) = hz;
    }
    #pragma unroll
    for (int r = 0; r < 4; r++) {
        const int row = q * 4 + r;   // D row = token index in tile
        sW[((0 + (c >> 3)) * 16 + row) * 8 + (c & 7)] = (u16)cvtpk(fmaxf(h0[r], 0.0f), 0.0f);
        sW[((2 + (c >> 3)) * 16 + row) * 8 + (c & 7)] = (u16)cvtpk(fmaxf(h1[r], 0.0f), 0.0f);
        sW[((4 + (c >> 3)) * 16 + row) * 8 + (c & 7)] = (u16)cvtpk(fmaxf(h2[r], 0.0f), 0.0f);
    }

    // GEMM2: out[16x88] = H[16x64] * B2[64x96]
    f32x4 o0 = {0,0,0,0}, o1 = {0,0,0,0}, o2 = {0,0,0,0};
    f32x4 o3 = {0,0,0,0}, o4 = {0,0,0,0}, o5 = {0,0,0,0};
    #pragma unroll
    for (int ks = 0; ks < 2; ks++) {
        bf16x8 a2 = *(const bf16x8*)(sW + ((ks * 4 + q) * 16 + c) * 8);
        bf16x8 w0 = *(const bf16x8*)(f2 + (ks * 384 +  0) * 8);
        bf16x8 w1 = *(const bf16x8*)(f2 + (ks * 384 + 16) * 8);
        bf16x8 w2 = *(const bf16x8*)(f2 + (ks * 384 + 32) * 8);
        bf16x8 w3 = *(const bf16x8*)(f2 + (ks * 384 + 48) * 8);
        bf16x8 w4 = *(const bf16x8*)(f2 + (ks * 384 + 64) * 8);
        bf16x8 w5 = *(const bf16x8*)(f2 + (ks * 384 + 80) * 8);
        o0 = __builtin_amdgcn_mfma_f32_16x16x32_bf16(a2, w0, o0, 0, 0, 0);
        o1 = __builtin_amdgcn_mfma_f32_16x16x32_bf16(a2, w1, o1, 0, 0, 0);
        o2 = __builtin_amdgcn_mfma_f32_16x16x32_bf16(a2, w2, o2, 0, 0, 0);
        o3 = __builtin_amdgcn_mfma_f32_16x16x32_bf16(a2, w3, o3, 0, 0, 0);
        o4 = __builtin_amdgcn_mfma_f32_16x16x32_bf16(a2, w4, o4, 0, 0, 0);
        o5 = __builtin_amdgcn_mfma_f32_16x16x32_bf16(a2, w5, o5, 0, 0, 0);
    }

    // store: D row = token (q*4+r), col d = nt*16 + c — 24 dword stores,
    // pairwise >= 64B apart (unmergeable), so the vmcnt bookkeeping in the
    // main loop (24 stores/tile) is stable against compiler merging.
    float* orow = out + (size_t)(tb + q * 4) * 88;
    #pragma unroll
    for (int r = 0; r < 4; r++) {
        orow[r * 88 +  0 + c] = o0[r];
        orow[r * 88 + 16 + c] = o1[r];
        orow[r * 88 + 32 + c] = o2[r];
        orow[r * 88 + 48 + c] = o3[r];
        orow[r * 88 + 64 + c] = o4[r];
        if (c < 8) orow[r * 88 + 80 + c] = o5[r];
    }
}

// ---------------- main ----------------
__global__ __launch_bounds__(256, 2)
void tones_v11(const int* __restrict__ widx, const int* __restrict__ xidx,
               const float* __restrict__ y,
               const float* __restrict__ Wconv, const float* __restrict__ bconv,
               const u16* __restrict__ wsb,
               float* __restrict__ out)
{
    // [0, 16896)                          weight image (u16 units)
    // 16896 + wave*5632 + {0,2816}        per-wave y double buffer (H in head)
    __shared__ __align__(16) u16 lds[16896 + 4 * 2 * YB_U16];   // 78848 B

    const int tid = threadIdx.x;
    const int wave = tid >> 6, lane = tid & 63;
    const int q = lane >> 4, c = lane & 15;
    const int base = blockIdx.x * 256 + wave * 64;       // 64 tokens per wave

    // idx loads (8 VMEM; required complete by the t=0 vmcnt(7))
    int xv[4], wv[4];
    #pragma unroll
    for (int t = 0; t < 4; t++) {
        xv[t] = xidx[base + t * 16 + c];
        wv[t] = widx[base + t * 16 + c];
    }

    u16* buf0 = lds + W_U16 + wave * (2 * YB_U16);
    u16* buf1 = buf0 + YB_U16;

    // y0 (7 VMEM)
    stage_y(y + (size_t)base * 88, buf0, lane);

    // weight image: 528 chunks/wave = 8 full + 1 quarter (9 VMEM)
    {
        const int wb = wave * 528;
        #pragma unroll
        for (int i = 0; i < 8; i++) {
            const int cb = wb + i * 64;
            gll16((const char*)wsb + (cb + lane) * 16, (char*)lds + cb * 16);
        }
        if (lane < 16) {
            const int cb = wb + 512;
            gll16((const char*)wsb + (cb + lane) * 16, (char*)lds + cb * 16);
        }
    }

    // y1 prefetch (7 VMEM) — stays in flight across the t=0 wait+barrier
    stage_y(y + (size_t)(base + 16) * 88, buf1, lane);

    const float wc00 = Wconv[0], wc01 = Wconv[1], wc02 = Wconv[2];
    const float wc10 = Wconv[3], wc11 = Wconv[4], wc12 = Wconv[5];
    const float bc0 = bconv[0], bc1 = bconv[1];

    // ---- t = 0: drain everything except y1's 7 loads; barrier for weights ----
    asm volatile("s_waitcnt vmcnt(7)" ::: "memory");
    __builtin_amdgcn_s_barrier();
    compute_tile(lds, buf0, wc00, wc01, wc02, wc10, wc11, wc12, bc0, bc1,
                 xv[0], wv[0], q, c, base + 0 * 16, out);

    // ---- t = 1: y2 prefetch; y1 done iff outstanding <= 24 stores + 7 = 31 ----
    stage_y(y + (size_t)(base + 2 * 16) * 88, buf0, lane);
    asm volatile("s_waitcnt vmcnt(28)" ::: "memory");
    compute_tile(lds, buf1, wc00, wc01, wc02, wc10, wc11, wc12, bc0, bc1,
                 xv[1], wv[1], q, c, base + 1 * 16, out);

    // ---- t = 2: y3 prefetch; y2 done iff outstanding <= 31 ----
    stage_y(y + (size_t)(base + 3 * 16) * 88, buf1, lane);
    asm volatile("s_waitcnt vmcnt(28)" ::: "memory");
    compute_tile(lds, buf0, wc00, wc01, wc02, wc10, wc11, wc12, bc0, bc1,
                 xv[2], wv[2], q, c, base + 2 * 16, out);

    // ---- t = 3: y3 done iff outstanding <= 24 (stores of t=2) ----
    asm volatile("s_waitcnt vmcnt(20)" ::: "memory");
    compute_tile(lds, buf1, wc00, wc01, wc02, wc10, wc11, wc12, bc0, bc1,
                 xv[3], wv[3], q, c, base + 3 * 16, out);
}

extern "C" void kernel_launch(void* const* d_in, const int* in_sizes, int n_in,
                              void* d_out, int out_size, void* d_ws, size_t ws_size,
                              hipStream_t stream) {
    (void)in_sizes; (void)n_in; (void)out_size; (void)ws_size;
    u16* ws = (u16*)d_ws;
    prep_weights<<<dim3(66), dim3(TPB), 0, stream>>>(
        (const float*)d_in[3],  (const float*)d_in[4],
        (const float*)d_in[5],  (const float*)d_in[6],
        (const float*)d_in[7],  (const float*)d_in[8],
        (const float*)d_in[11], (const float*)d_in[12], ws);
    tones_v11<<<dim3(NTOK / 256), dim3(TPB), 0, stream>>>(
        (const int*)d_in[0], (const int*)d_in[1], (const float*)d_in[2],
        (const float*)d_in[9], (const float*)d_in[10], ws, (float*)d_out);
}

// Round 7
// 123.761 us; speedup vs baseline: 1.0241x; 1.0241x over previous
//
#include <hip/hip_runtime.h>
#include <stdint.h>

// B=256, T=512, f32. v12: GEMM1 computed with SWAPPED operands -> H^T in
// registers, whose C/D layout (lane (q,c) holds H[token=c][n=16nt+4q+i])
// feeds GEMM2's A-operand after a pure in-register lane permutation:
// 12 ds_bpermute + cndmask selects replace the entire H LDS round-trip
// (12 ds_write_b16 + 2 ds_read_b128 + 2 LDS latencies) of v8-v11.
// TPB 512 (8 waves/block, grid 1024): weight image staged once per 512
// threads (264 chunks/wave), y per-wave via global_load_lds, single
// __syncthreads. LDS 78.8 KB -> 2 blocks/CU (16 waves/CU).
#define NTOK (256 * 512)

typedef short bf16x8 __attribute__((ext_vector_type(8)));
typedef float f32x4 __attribute__((ext_vector_type(4)));
typedef unsigned int u32x4 __attribute__((ext_vector_type(4)));
typedef unsigned short u16;
typedef unsigned int u32;

union Frag { bf16x8 h; u32x4 w; };

#define B1_U16 10752   // 28 chunks * 48 cols * 8 u16
#define B2_U16 6144    // 8 chunks * 96 cols * 8 u16
#define W_U16 (B1_U16 + B2_U16)               // 16896 u16 = 33792 B, 2112 chunks
#define YB_U16 2816                           // 5632 B y tile buffer

__device__ __forceinline__ u16 f2bf(float f) {
    u32 u = __float_as_uint(f);
    return (u16)((u + 0x7fffu + ((u >> 16) & 1u)) >> 16);  // rne
}
__device__ __forceinline__ u32 cvtpk(float lo, float hi) {
    u32 r;
    asm("v_cvt_pk_bf16_f32 %0, %1, %2" : "=v"(r) : "v"(lo), "v"(hi));
    return r;
}
__device__ __forceinline__ void gll16(const void* g, void* l) {
    __builtin_amdgcn_global_load_lds(
        (const __attribute__((address_space(1))) void*)g,
        (__attribute__((address_space(3))) void*)l, 16, 0, 0);
}
__device__ __forceinline__ void gll4(const void* g, void* l) {
    __builtin_amdgcn_global_load_lds(
        (const __attribute__((address_space(1))) void*)g,
        (__attribute__((address_space(3))) void*)l, 4, 0, 0);
}

// ---------------- prep: build fragment-ordered bf16 weight image ----------------
__global__ __launch_bounds__(256, 1)
void prep_weights(const float* __restrict__ Wxh, const float* __restrict__ bxh,
                  const float* __restrict__ Wwh, const float* __restrict__ bwh,
                  const float* __restrict__ Wyh, const float* __restrict__ byh,
                  const float* __restrict__ Whl, const float* __restrict__ bhl,
                  u16* __restrict__ ws)
{
    int e = blockIdx.x * 256 + threadIdx.x;
    if (e < B1_U16) {
        int j = e & 7, n = (e >> 3) % 48, kc = e / 384;
        int k = kc * 8 + j;                  // k = 2*d + ch for k<176
        float v;
        if (k < 176)       v = Wyh[n * 176 + (k & 1) * 88 + (k >> 1)];
        else if (k < 192)  v = Wxh[n * 16 + (k - 176)];   // x-onehot rows
        else if (k < 208)  v = Wwh[n * 16 + (k - 192)];   // w-onehot rows
        else if (k == 208) v = bxh[n] + bwh[n] + byh[n];  // bias row
        else               v = 0.0f;
        ws[e] = f2bf(v);
    } else if (e < B1_U16 + B2_U16) {
        int e2 = e - B1_U16;
        int j = e2 & 7, dd = (e2 >> 3) % 96, kc = e2 / 768;
        int k = kc * 8 + j;
        float v = 0.0f;
        if (dd < 88) {
            if (k < 48)       v = Whl[dd * 48 + k];
            else if (k == 48) v = bhl[dd];
        }
        ws[e] = f2bf(v);
    }
}

// ---------------- main ----------------
__global__ __launch_bounds__(512, 4)
void tones_v12(const int* __restrict__ widx, const int* __restrict__ xidx,
               const float* __restrict__ y,
               const float* __restrict__ Wconv, const float* __restrict__ bconv,
               const u16* __restrict__ wsb,
               float* __restrict__ out)
{
    // [0, 16896)                       weight image (u16 units)
    // 16896 + wave*2816                per-wave y tile (1408 f32)
    __shared__ __align__(16) u16 lds[W_U16 + 8 * YB_U16];   // 78848 B

    const int tid = threadIdx.x;
    const int wave = tid >> 6, lane = tid & 63;
    const int q = lane >> 4, c = lane & 15;

    const int tb = blockIdx.x * 128 + wave * 16;         // 16 tokens per wave

    // idx loads (2 VMEM)
    const int xv = xidx[tb + c];
    const int wv = widx[tb + c];

    // ---- stage this wave's y tile (contiguous 5632 B) into LDS: 7 VMEM ----
    u16* sYu = lds + W_U16 + wave * YB_U16;
    {
        const char* yt = (const char*)(y + (size_t)tb * 88);
        char* dst = (char*)sYu;
        #pragma unroll
        for (int j = 0; j < 5; j++)
            gll16(yt + j * 1024 + lane * 16, dst + j * 1024);
        #pragma unroll
        for (int k = 0; k < 2; k++)
            gll4(yt + 5120 + k * 256 + lane * 4, dst + 5120 + k * 256);
    }

    // ---- stage weight image: 2112 chunks / 8 waves = 264/wave (5 VMEM) ----
    {
        const int wb = wave * 264;
        #pragma unroll
        for (int i = 0; i < 4; i++) {
            const int cb = wb + i * 64;
            gll16((const char*)wsb + (cb + lane) * 16, (char*)lds + cb * 16);
        }
        if (lane < 8) {
            const int cb = wb + 256;
            gll16((const char*)wsb + (cb + lane) * 16, (char*)lds + cb * 16);
        }
    }

    const float wc00 = Wconv[0], wc01 = Wconv[1], wc02 = Wconv[2];
    const float wc10 = Wconv[3], wc11 = Wconv[4], wc12 = Wconv[5];
    const float bc0 = bconv[0], bc1 = bconv[1];

    __syncthreads();   // drains vmcnt + makes weights/y visible

    const float* yr = (const float*)sYu + c * 88;        // this lane's token row

    // B1 frag (ks,nt) at u16 index ((ks*4+q)*48 + nt*16 + c)*8
    const u16* f1 = lds + (q * 48 + c) * 8;
    // B2 frag (ks,nt) at u16 index B1_U16 + ((ks*4+q)*96 + nt*16 + c)*8
    const u16* f2 = lds + B1_U16 + (q * 96 + c) * 8;

    // ---- GEMM1 (swapped): h_nt = B1^T-as-A x af-as-B => H^T ----
    // D layout: lane (q,c) holds H[token=c][n = 16*nt + 4*q + i], i=0..3
    f32x4 h0 = {0, 0, 0, 0}, h1 = {0, 0, 0, 0}, h2 = {0, 0, 0, 0};
    #pragma unroll
    for (int ks = 0; ks < 7; ks++) {
        Frag af;
        if (ks < 5) {
            const int d0 = 16 * ks + 4 * q;
            float p0 = (d0 == 0) ? 0.0f : yr[d0 - 1];
            f32x4 v4 = *(const f32x4*)(yr + d0);
            float p5 = yr[d0 + 4];                       // d0+4 <= 80 < 88
            float p[6] = {p0, v4[0], v4[1], v4[2], v4[3], p5};
            #pragma unroll
            for (int i = 0; i < 4; i++) {
                float c0 = fmaf(wc00, p[i], fmaf(wc01, p[i + 1], fmaf(wc02, p[i + 2], bc0)));
                float c1 = fmaf(wc10, p[i], fmaf(wc11, p[i + 1], fmaf(wc12, p[i + 2], bc1)));
                af.w[i] = cvtpk(fmaxf(c0, 0.0f), fmaxf(c1, 0.0f));
            }
        } else if (ks == 5) {
            if (q < 2) {
                const int d0 = 80 + 4 * q;
                float p0 = yr[d0 - 1];
                f32x4 v4 = *(const f32x4*)(yr + d0);
                float p5 = (q == 0) ? yr[84] : 0.0f;     // right edge pad at d=87
                float p[6] = {p0, v4[0], v4[1], v4[2], v4[3], p5};
                #pragma unroll
                for (int i = 0; i < 4; i++) {
                    float c0 = fmaf(wc00, p[i], fmaf(wc01, p[i + 1], fmaf(wc02, p[i + 2], bc0)));
                    float c1 = fmaf(wc10, p[i], fmaf(wc11, p[i + 1], fmaf(wc12, p[i + 2], bc1)));
                    af.w[i] = cvtpk(fmaxf(c0, 0.0f), fmaxf(c1, 0.0f));
                }
            } else {
                const int base = (q - 2) * 8;
                #pragma unroll
                for (int i = 0; i < 4; i++) {
                    u32 lo = (base + 2 * i     == xv) ? 0x3F80u : 0u;
                    u32 hi = (base + 2 * i + 1 == xv) ? 0x3F800000u : 0u;
                    af.w[i] = lo | hi;
                }
            }
        } else {
            if (q < 2) {
                const int base = q * 8;
                #pragma unroll
                for (int i = 0; i < 4; i++) {
                    u32 lo = (base + 2 * i     == wv) ? 0x3F80u : 0u;
                    u32 hi = (base + 2 * i + 1 == wv) ? 0x3F800000u : 0u;
                    af.w[i] = lo | hi;
                }
            } else {
                af.w = (u32x4){(q == 2) ? 0x3F80u : 0u, 0u, 0u, 0u};
            }
        }
        bf16x8 b0 = *(const bf16x8*)(f1 + (ks * 192 +  0) * 8);
        bf16x8 b1 = *(const bf16x8*)(f1 + (ks * 192 + 16) * 8);
        bf16x8 b2 = *(const bf16x8*)(f1 + (ks * 192 + 32) * 8);
        h0 = __builtin_amdgcn_mfma_f32_16x16x32_bf16(b0, af.h, h0, 0, 0, 0);
        h1 = __builtin_amdgcn_mfma_f32_16x16x32_bf16(b1, af.h, h1, 0, 0, 0);
        h2 = __builtin_amdgcn_mfma_f32_16x16x32_bf16(b2, af.h, h2, 0, 0, 0);
    }

    // ---- relu + pack: pk[nt][p] = bf16(H[c][16nt+4q+2p], H[c][16nt+4q+2p+1]) ----
    u32 pk00 = cvtpk(fmaxf(h0[0], 0.0f), fmaxf(h0[1], 0.0f));
    u32 pk01 = cvtpk(fmaxf(h0[2], 0.0f), fmaxf(h0[3], 0.0f));
    u32 pk10 = cvtpk(fmaxf(h1[0], 0.0f), fmaxf(h1[1], 0.0f));
    u32 pk11 = cvtpk(fmaxf(h1[2], 0.0f), fmaxf(h1[3], 0.0f));
    u32 pk20 = cvtpk(fmaxf(h2[0], 0.0f), fmaxf(h2[1], 0.0f));
    u32 pk21 = cvtpk(fmaxf(h2[2], 0.0f), fmaxf(h2[3], 0.0f));

    // ---- in-register transpose to GEMM2 A-frags via ds_bpermute ----
    // target lane (q,c) ks=0 needs n=8q+j from lanes ((2q)&3, c) / ((2q+1)&3, c),
    // register nt = q>>1; ks=1 (n=32+8q+j) from nt=2 (q<2), constants (q>=2).
    const int a0 = ((((2 * q) & 3) * 16 + c) * 4);
    const int a1 = a0 + 64;
    u32 A00 = (u32)__builtin_amdgcn_ds_bpermute(a0, (int)pk00);
    u32 A01 = (u32)__builtin_amdgcn_ds_bpermute(a0, (int)pk01);
    u32 B00 = (u32)__builtin_amdgcn_ds_bpermute(a1, (int)pk00);
    u32 B01 = (u32)__builtin_amdgcn_ds_bpermute(a1, (int)pk01);
    u32 A10 = (u32)__builtin_amdgcn_ds_bpermute(a0, (int)pk10);
    u32 A11 = (u32)__builtin_amdgcn_ds_bpermute(a0, (int)pk11);
    u32 B10 = (u32)__builtin_amdgcn_ds_bpermute(a1, (int)pk10);
    u32 B11 = (u32)__builtin_amdgcn_ds_bpermute(a1, (int)pk11);
    u32 A20 = (u32)__builtin_amdgcn_ds_bpermute(a0, (int)pk20);
    u32 A21 = (u32)__builtin_amdgcn_ds_bpermute(a0, (int)pk21);
    u32 B20 = (u32)__builtin_amdgcn_ds_bpermute(a1, (int)pk20);
    u32 B21 = (u32)__builtin_amdgcn_ds_bpermute(a1, (int)pk21);

    const bool hi = (q >= 2);
    Frag a2k0, a2k1;
    a2k0.w[0] = hi ? A10 : A00;
    a2k0.w[1] = hi ? A11 : A01;
    a2k0.w[2] = hi ? B10 : B00;
    a2k0.w[3] = hi ? B11 : B01;
    a2k1.w[0] = !hi ? A20 : ((q == 2) ? 0x3F80u : 0u);   // k2=48 bias one
    a2k1.w[1] = !hi ? A21 : 0u;
    a2k1.w[2] = !hi ? B20 : 0u;
    a2k1.w[3] = !hi ? B21 : 0u;

    // ---- GEMM2: out[16x88] = H[16x64] * B2[64x96] ----
    f32x4 o0 = {0,0,0,0}, o1 = {0,0,0,0}, o2 = {0,0,0,0};
    f32x4 o3 = {0,0,0,0}, o4 = {0,0,0,0}, o5 = {0,0,0,0};
    #pragma unroll
    for (int ks = 0; ks < 2; ks++) {
        bf16x8 a2 = (ks == 0) ? a2k0.h : a2k1.h;
        bf16x8 w0 = *(const bf16x8*)(f2 + (ks * 384 +  0) * 8);
        bf16x8 w1 = *(const bf16x8*)(f2 + (ks * 384 + 16) * 8);
        bf16x8 w2 = *(const bf16x8*)(f2 + (ks * 384 + 32) * 8);
        bf16x8 w3 = *(const bf16x8*)(f2 + (ks * 384 + 48) * 8);
        bf16x8 w4 = *(const bf16x8*)(f2 + (ks * 384 + 64) * 8);
        bf16x8 w5 = *(const bf16x8*)(f2 + (ks * 384 + 80) * 8);
        o0 = __builtin_amdgcn_mfma_f32_16x16x32_bf16(a2, w0, o0, 0, 0, 0);
        o1 = __builtin_amdgcn_mfma_f32_16x16x32_bf16(a2, w1, o1, 0, 0, 0);
        o2 = __builtin_amdgcn_mfma_f32_16x16x32_bf16(a2, w2, o2, 0, 0, 0);
        o3 = __builtin_amdgcn_mfma_f32_16x16x32_bf16(a2, w3, o3, 0, 0, 0);
        o4 = __builtin_amdgcn_mfma_f32_16x16x32_bf16(a2, w4, o4, 0, 0, 0);
        o5 = __builtin_amdgcn_mfma_f32_16x16x32_bf16(a2, w5, o5, 0, 0, 0);
    }

    // ---- store: D row = token (q*4+r), col d = nt*16 + c ----
    float* orow = out + (size_t)(tb + q * 4) * 88;
    #pragma unroll
    for (int r = 0; r < 4; r++) {
        orow[r * 88 +  0 + c] = o0[r];
        orow[r * 88 + 16 + c] = o1[r];
        orow[r * 88 + 32 + c] = o2[r];
        orow[r * 88 + 48 + c] = o3[r];
        orow[r * 88 + 64 + c] = o4[r];
        if (c < 8) orow[r * 88 + 80 + c] = o5[r];
    }
}

extern "C" void kernel_launch(void* const* d_in, const int* in_sizes, int n_in,
                              void* d_out, int out_size, void* d_ws, size_t ws_size,
                              hipStream_t stream) {
    (void)in_sizes; (void)n_in; (void)out_size; (void)ws_size;
    u16* ws = (u16*)d_ws;
    prep_weights<<<dim3(66), dim3(256), 0, stream>>>(
        (const float*)d_in[3],  (const float*)d_in[4],
        (const float*)d_in[5],  (const float*)d_in[6],
        (const float*)d_in[7],  (const float*)d_in[8],
        (const float*)d_in[11], (const float*)d_in[12], ws);
    tones_v12<<<dim3(NTOK / 128), dim3(512), 0, stream>>>(
        (const int*)d_in[0], (const int*)d_in[1], (const float*)d_in[2],
        (const float*)d_in[9], (const float*)d_in[10], ws, (float*)d_out);
}

// Round 8
// 123.313 us; speedup vs baseline: 1.0279x; 1.0036x over previous
//
#include <hip/hip_runtime.h>
#include <stdint.h>

// B=256, T=512, f32. v13 = v12 + swapped GEMM2: out^T = W2^T x H^T computed
// as mfma(w_frag-as-A, a2k-as-B). The same f2 fragments serve as A-operand
// (lane (q,c) -> W2^T[16nt+c][8q+j]) and the same bpermute'd a2k fragments
// serve as B-operand (A/B layouts share the index map). D-layout then gives
// lane (q,c) = out[tok=c][d=16nt+4q+i], i.e. 4 CONSECUTIVE d per lane:
// stores collapse from 24 scattered dwords to 5+1 dwordx4, fully coalesced
// (q=0..3 at fixed c cover 64 contiguous bytes). GEMM1 swapped + bpermute
// H-transpose as v12. TPB 512, grid 1024, weights staged once/block,
// y per-wave via global_load_lds, one __syncthreads, 2 blocks/CU.
#define NTOK (256 * 512)

typedef short bf16x8 __attribute__((ext_vector_type(8)));
typedef float f32x4 __attribute__((ext_vector_type(4)));
typedef unsigned int u32x4 __attribute__((ext_vector_type(4)));
typedef unsigned short u16;
typedef unsigned int u32;

union Frag { bf16x8 h; u32x4 w; };

#define B1_U16 10752   // 28 chunks * 48 cols * 8 u16
#define B2_U16 6144    // 8 chunks * 96 cols * 8 u16
#define W_U16 (B1_U16 + B2_U16)               // 16896 u16 = 33792 B, 2112 chunks
#define YB_U16 2816                           // 5632 B y tile buffer

__device__ __forceinline__ u16 f2bf(float f) {
    u32 u = __float_as_uint(f);
    return (u16)((u + 0x7fffu + ((u >> 16) & 1u)) >> 16);  // rne
}
__device__ __forceinline__ u32 cvtpk(float lo, float hi) {
    u32 r;
    asm("v_cvt_pk_bf16_f32 %0, %1, %2" : "=v"(r) : "v"(lo), "v"(hi));
    return r;
}
__device__ __forceinline__ void gll16(const void* g, void* l) {
    __builtin_amdgcn_global_load_lds(
        (const __attribute__((address_space(1))) void*)g,
        (__attribute__((address_space(3))) void*)l, 16, 0, 0);
}
__device__ __forceinline__ void gll4(const void* g, void* l) {
    __builtin_amdgcn_global_load_lds(
        (const __attribute__((address_space(1))) void*)g,
        (__attribute__((address_space(3))) void*)l, 4, 0, 0);
}

// ---------------- prep: build fragment-ordered bf16 weight image ----------------
__global__ __launch_bounds__(256, 1)
void prep_weights(const float* __restrict__ Wxh, const float* __restrict__ bxh,
                  const float* __restrict__ Wwh, const float* __restrict__ bwh,
                  const float* __restrict__ Wyh, const float* __restrict__ byh,
                  const float* __restrict__ Whl, const float* __restrict__ bhl,
                  u16* __restrict__ ws)
{
    int e = blockIdx.x * 256 + threadIdx.x;
    if (e < B1_U16) {
        int j = e & 7, n = (e >> 3) % 48, kc = e / 384;
        int k = kc * 8 + j;                  // k = 2*d + ch for k<176
        float v;
        if (k < 176)       v = Wyh[n * 176 + (k & 1) * 88 + (k >> 1)];
        else if (k < 192)  v = Wxh[n * 16 + (k - 176)];   // x-onehot rows
        else if (k < 208)  v = Wwh[n * 16 + (k - 192)];   // w-onehot rows
        else if (k == 208) v = bxh[n] + bwh[n] + byh[n];  // bias row
        else               v = 0.0f;
        ws[e] = f2bf(v);
    } else if (e < B1_U16 + B2_U16) {
        int e2 = e - B1_U16;
        int j = e2 & 7, dd = (e2 >> 3) % 96, kc = e2 / 768;
        int k = kc * 8 + j;
        float v = 0.0f;
        if (dd < 88) {
            if (k < 48)       v = Whl[dd * 48 + k];
            else if (k == 48) v = bhl[dd];
        }
        ws[e] = f2bf(v);
    }
}

// ---------------- main ----------------
__global__ __launch_bounds__(512, 4)
void tones_v13(const int* __restrict__ widx, const int* __restrict__ xidx,
               const float* __restrict__ y,
               const float* __restrict__ Wconv, const float* __restrict__ bconv,
               const u16* __restrict__ wsb,
               float* __restrict__ out)
{
    // [0, 16896)                       weight image (u16 units)
    // 16896 + wave*2816                per-wave y tile (1408 f32)
    __shared__ __align__(16) u16 lds[W_U16 + 8 * YB_U16];   // 78848 B

    const int tid = threadIdx.x;
    const int wave = tid >> 6, lane = tid & 63;
    const int q = lane >> 4, c = lane & 15;

    const int tb = blockIdx.x * 128 + wave * 16;         // 16 tokens per wave

    // idx loads (2 VMEM)
    const int xv = xidx[tb + c];
    const int wv = widx[tb + c];

    // ---- stage this wave's y tile (contiguous 5632 B) into LDS: 7 VMEM ----
    u16* sYu = lds + W_U16 + wave * YB_U16;
    {
        const char* yt = (const char*)(y + (size_t)tb * 88);
        char* dst = (char*)sYu;
        #pragma unroll
        for (int j = 0; j < 5; j++)
            gll16(yt + j * 1024 + lane * 16, dst + j * 1024);
        #pragma unroll
        for (int k = 0; k < 2; k++)
            gll4(yt + 5120 + k * 256 + lane * 4, dst + 5120 + k * 256);
    }

    // ---- stage weight image: 2112 chunks / 8 waves = 264/wave (5 VMEM) ----
    {
        const int wb = wave * 264;
        #pragma unroll
        for (int i = 0; i < 4; i++) {
            const int cb = wb + i * 64;
            gll16((const char*)wsb + (cb + lane) * 16, (char*)lds + cb * 16);
        }
        if (lane < 8) {
            const int cb = wb + 256;
            gll16((const char*)wsb + (cb + lane) * 16, (char*)lds + cb * 16);
        }
    }

    const float wc00 = Wconv[0], wc01 = Wconv[1], wc02 = Wconv[2];
    const float wc10 = Wconv[3], wc11 = Wconv[4], wc12 = Wconv[5];
    const float bc0 = bconv[0], bc1 = bconv[1];

    __syncthreads();   // drains vmcnt + makes weights/y visible

    const float* yr = (const float*)sYu + c * 88;        // this lane's token row

    // B1 frag (ks,nt) at u16 index ((ks*4+q)*48 + nt*16 + c)*8
    const u16* f1 = lds + (q * 48 + c) * 8;
    // B2 frag (ks,nt) at u16 index B1_U16 + ((ks*4+q)*96 + nt*16 + c)*8
    const u16* f2 = lds + B1_U16 + (q * 96 + c) * 8;

    // ---- GEMM1 (swapped): h_nt = B1^T-as-A x af-as-B => H^T ----
    // D layout: lane (q,c) holds H[token=c][n = 16*nt + 4*q + i], i=0..3
    f32x4 h0 = {0, 0, 0, 0}, h1 = {0, 0, 0, 0}, h2 = {0, 0, 0, 0};
    #pragma unroll
    for (int ks = 0; ks < 7; ks++) {
        Frag af;
        if (ks < 5) {
            const int d0 = 16 * ks + 4 * q;
            float p0 = (d0 == 0) ? 0.0f : yr[d0 - 1];
            f32x4 v4 = *(const f32x4*)(yr + d0);
            float p5 = yr[d0 + 4];                       // d0+4 <= 80 < 88
            float p[6] = {p0, v4[0], v4[1], v4[2], v4[3], p5};
            #pragma unroll
            for (int i = 0; i < 4; i++) {
                float c0 = fmaf(wc00, p[i], fmaf(wc01, p[i + 1], fmaf(wc02, p[i + 2], bc0)));
                float c1 = fmaf(wc10, p[i], fmaf(wc11, p[i + 1], fmaf(wc12, p[i + 2], bc1)));
                af.w[i] = cvtpk(fmaxf(c0, 0.0f), fmaxf(c1, 0.0f));
            }
        } else if (ks == 5) {
            if (q < 2) {
                const int d0 = 80 + 4 * q;
                float p0 = yr[d0 - 1];
                f32x4 v4 = *(const f32x4*)(yr + d0);
                float p5 = (q == 0) ? yr[84] : 0.0f;     // right edge pad at d=87
                float p[6] = {p0, v4[0], v4[1], v4[2], v4[3], p5};
                #pragma unroll
                for (int i = 0; i < 4; i++) {
                    float c0 = fmaf(wc00, p[i], fmaf(wc01, p[i + 1], fmaf(wc02, p[i + 2], bc0)));
                    float c1 = fmaf(wc10, p[i], fmaf(wc11, p[i + 1], fmaf(wc12, p[i + 2], bc1)));
                    af.w[i] = cvtpk(fmaxf(c0, 0.0f), fmaxf(c1, 0.0f));
                }
            } else {
                const int base = (q - 2) * 8;
                #pragma unroll
                for (int i = 0; i < 4; i++) {
                    u32 lo = (base + 2 * i     == xv) ? 0x3F80u : 0u;
                    u32 hi = (base + 2 * i + 1 == xv) ? 0x3F800000u : 0u;
                    af.w[i] = lo | hi;
                }
            }
        } else {
            if (q < 2) {
                const int base = q * 8;
                #pragma unroll
                for (int i = 0; i < 4; i++) {
                    u32 lo = (base + 2 * i     == wv) ? 0x3F80u : 0u;
                    u32 hi = (base + 2 * i + 1 == wv) ? 0x3F800000u : 0u;
                    af.w[i] = lo | hi;
                }
            } else {
                af.w = (u32x4){(q == 2) ? 0x3F80u : 0u, 0u, 0u, 0u};
            }
        }
        bf16x8 b0 = *(const bf16x8*)(f1 + (ks * 192 +  0) * 8);
        bf16x8 b1 = *(const bf16x8*)(f1 + (ks * 192 + 16) * 8);
        bf16x8 b2 = *(const bf16x8*)(f1 + (ks * 192 + 32) * 8);
        h0 = __builtin_amdgcn_mfma_f32_16x16x32_bf16(b0, af.h, h0, 0, 0, 0);
        h1 = __builtin_amdgcn_mfma_f32_16x16x32_bf16(b1, af.h, h1, 0, 0, 0);
        h2 = __builtin_amdgcn_mfma_f32_16x16x32_bf16(b2, af.h, h2, 0, 0, 0);
    }

    // ---- relu + pack: pk[nt][p] = bf16(H[c][16nt+4q+2p], H[c][16nt+4q+2p+1]) ----
    u32 pk00 = cvtpk(fmaxf(h0[0], 0.0f), fmaxf(h0[1], 0.0f));
    u32 pk01 = cvtpk(fmaxf(h0[2], 0.0f), fmaxf(h0[3], 0.0f));
    u32 pk10 = cvtpk(fmaxf(h1[0], 0.0f), fmaxf(h1[1], 0.0f));
    u32 pk11 = cvtpk(fmaxf(h1[2], 0.0f), fmaxf(h1[3], 0.0f));
    u32 pk20 = cvtpk(fmaxf(h2[0], 0.0f), fmaxf(h2[1], 0.0f));
    u32 pk21 = cvtpk(fmaxf(h2[2], 0.0f), fmaxf(h2[3], 0.0f));

    // ---- in-register transpose to GEMM2 H-frags via ds_bpermute ----
    // target lane (q,c) ks=0 needs n=8q+j from lanes ((2q)&3, c) / ((2q+1)&3, c),
    // register nt = q>>1; ks=1 (n=32+8q+j) from nt=2 (q<2), constants (q>=2).
    const int a0 = ((((2 * q) & 3) * 16 + c) * 4);
    const int a1 = a0 + 64;
    u32 A00 = (u32)__builtin_amdgcn_ds_bpermute(a0, (int)pk00);
    u32 A01 = (u32)__builtin_amdgcn_ds_bpermute(a0, (int)pk01);
    u32 B00 = (u32)__builtin_amdgcn_ds_bpermute(a1, (int)pk00);
    u32 B01 = (u32)__builtin_amdgcn_ds_bpermute(a1, (int)pk01);
    u32 A10 = (u32)__builtin_amdgcn_ds_bpermute(a0, (int)pk10);
    u32 A11 = (u32)__builtin_amdgcn_ds_bpermute(a0, (int)pk11);
    u32 B10 = (u32)__builtin_amdgcn_ds_bpermute(a1, (int)pk10);
    u32 B11 = (u32)__builtin_amdgcn_ds_bpermute(a1, (int)pk11);
    u32 A20 = (u32)__builtin_amdgcn_ds_bpermute(a0, (int)pk20);
    u32 A21 = (u32)__builtin_amdgcn_ds_bpermute(a0, (int)pk21);
    u32 B20 = (u32)__builtin_amdgcn_ds_bpermute(a1, (int)pk20);
    u32 B21 = (u32)__builtin_amdgcn_ds_bpermute(a1, (int)pk21);

    const bool hi = (q >= 2);
    Frag a2k0, a2k1;
    a2k0.w[0] = hi ? A10 : A00;
    a2k0.w[1] = hi ? A11 : A01;
    a2k0.w[2] = hi ? B10 : B00;
    a2k0.w[3] = hi ? B11 : B01;
    a2k1.w[0] = !hi ? A20 : ((q == 2) ? 0x3F80u : 0u);   // k2=48 bias one
    a2k1.w[1] = !hi ? A21 : 0u;
    a2k1.w[2] = !hi ? B20 : 0u;
    a2k1.w[3] = !hi ? B21 : 0u;

    // ---- GEMM2 (swapped): out^T = W2^T x H^T via mfma(w-as-A, a2k-as-B) ----
    // D layout: lane (q,c) holds out[token=c][d = 16*nt + 4*q + i], i=0..3
    f32x4 o0 = {0,0,0,0}, o1 = {0,0,0,0}, o2 = {0,0,0,0};
    f32x4 o3 = {0,0,0,0}, o4 = {0,0,0,0}, o5 = {0,0,0,0};
    #pragma unroll
    for (int ks = 0; ks < 2; ks++) {
        bf16x8 a2 = (ks == 0) ? a2k0.h : a2k1.h;
        bf16x8 w0 = *(const bf16x8*)(f2 + (ks * 384 +  0) * 8);
        bf16x8 w1 = *(const bf16x8*)(f2 + (ks * 384 + 16) * 8);
        bf16x8 w2 = *(const bf16x8*)(f2 + (ks * 384 + 32) * 8);
        bf16x8 w3 = *(const bf16x8*)(f2 + (ks * 384 + 48) * 8);
        bf16x8 w4 = *(const bf16x8*)(f2 + (ks * 384 + 64) * 8);
        bf16x8 w5 = *(const bf16x8*)(f2 + (ks * 384 + 80) * 8);
        o0 = __builtin_amdgcn_mfma_f32_16x16x32_bf16(w0, a2, o0, 0, 0, 0);
        o1 = __builtin_amdgcn_mfma_f32_16x16x32_bf16(w1, a2, o1, 0, 0, 0);
        o2 = __builtin_amdgcn_mfma_f32_16x16x32_bf16(w2, a2, o2, 0, 0, 0);
        o3 = __builtin_amdgcn_mfma_f32_16x16x32_bf16(w3, a2, o3, 0, 0, 0);
        o4 = __builtin_amdgcn_mfma_f32_16x16x32_bf16(w4, a2, o4, 0, 0, 0);
        o5 = __builtin_amdgcn_mfma_f32_16x16x32_bf16(w5, a2, o5, 0, 0, 0);
    }

    // ---- store: lane (q,c) writes out[tb+c][16nt+4q .. +3] as dwordx4 ----
    // lanes q=0..3 at fixed c cover 64 contiguous bytes; 16B aligned
    // (352|16, 64nt|16, 16q|16). nt=5 valid only for q<2 (d<88).
    float* ob = out + (size_t)(tb + c) * 88 + 4 * q;
    *(f32x4*)(ob +  0) = o0;
    *(f32x4*)(ob + 16) = o1;
    *(f32x4*)(ob + 32) = o2;
    *(f32x4*)(ob + 48) = o3;
    *(f32x4*)(ob + 64) = o4;
    if (q < 2) *(f32x4*)(ob + 80) = o5;
}

extern "C" void kernel_launch(void* const* d_in, const int* in_sizes, int n_in,
                              void* d_out, int out_size, void* d_ws, size_t ws_size,
                              hipStream_t stream) {
    (void)in_sizes; (void)n_in; (void)out_size; (void)ws_size;
    u16* ws = (u16*)d_ws;
    prep_weights<<<dim3(66), dim3(256), 0, stream>>>(
        (const float*)d_in[3],  (const float*)d_in[4],
        (const float*)d_in[5],  (const float*)d_in[6],
        (const float*)d_in[7],  (const float*)d_in[8],
        (const float*)d_in[11], (const float*)d_in[12], ws);
    tones_v13<<<dim3(NTOK / 128), dim3(512), 0, stream>>>(
        (const int*)d_in[0], (const int*)d_in[1], (const float*)d_in[2],
        (const float*)d_in[9], (const float*)d_in[10], ws, (float*)d_out);
}